// Round 3
// baseline (481.176 us; speedup 1.0000x reference)
//
#include <hip/hip_runtime.h>

// Morphological dilation (max-plus 3x3 conv), zero-padded.
// x: (B=4, C=64, H=512, W=512) fp32, weights: (C=64, 3, 3) fp32.
// out[b,c,h,w] = max_{i,j in 0..2} ( xp[b,c,h-1+i,w-1+j] + wt[c,i,j] ),
// where xp is ZERO-padded (nn.Unfold semantics) — padded zeros DO
// participate in the max with their weight.

#define BB 4
#define CC 64
#define HH 512
#define WW 512
#define W4 (WW / 4)

typedef float vfloat4 __attribute__((ext_vector_type(4)));

__global__ __launch_bounds__(256) void morph_dilate_kernel(
    const float* __restrict__ x,
    const float* __restrict__ wts,
    float* __restrict__ out) {
    // one thread per 4 consecutive outputs along W
    int tid = blockIdx.x * blockDim.x + threadIdx.x;
    // total threads = B*C*H*W4 = 4*64*512*128 = 16,777,216
    int w4    = (tid & (W4 - 1)) * 4;       // starting column (multiple of 4)
    int h     = (tid >> 7) & (HH - 1);      // row
    int plane = tid >> 16;                  // b*C + c
    int c     = plane & (CC - 1);

    const float* xplane = x + (size_t)plane * (HH * WW);
    const float* wt = wts + c * 9;

    // weights (uniform within block -> cached/broadcast)
    float w00 = wt[0], w01 = wt[1], w02 = wt[2];
    float w10 = wt[3], w11 = wt[4], w12 = wt[5];
    float w20 = wt[6], w21 = wt[7], w22 = wt[8];

    // load 3 input rows: 6 floats each (w4-1 .. w4+4), zero outside
    float v[3][6];
#pragma unroll
    for (int i = 0; i < 3; ++i) {
        int r = h - 1 + i;
        if (r >= 0 && r < HH) {
            const float* xrow = xplane + r * WW;
            v[i][0] = (w4 > 0) ? xrow[w4 - 1] : 0.0f;
            vfloat4 mid = *reinterpret_cast<const vfloat4*>(xrow + w4);
            v[i][1] = mid.x; v[i][2] = mid.y; v[i][3] = mid.z; v[i][4] = mid.w;
            v[i][5] = (w4 + 4 < WW) ? xrow[w4 + 4] : 0.0f;
        } else {
#pragma unroll
            for (int j = 0; j < 6; ++j) v[i][j] = 0.0f;
        }
    }

    vfloat4 o;
#pragma unroll
    for (int t = 0; t < 4; ++t) {
        float m;
        m =              v[0][t + 0] + w00;
        m = fmaxf(m,     v[0][t + 1] + w01);
        m = fmaxf(m,     v[0][t + 2] + w02);
        m = fmaxf(m,     v[1][t + 0] + w10);
        m = fmaxf(m,     v[1][t + 1] + w11);
        m = fmaxf(m,     v[1][t + 2] + w12);
        m = fmaxf(m,     v[2][t + 0] + w20);
        m = fmaxf(m,     v[2][t + 1] + w21);
        m = fmaxf(m,     v[2][t + 2] + w22);
        o[t] = m;
    }

    vfloat4* dst = reinterpret_cast<vfloat4*>(out + (size_t)tid * 4);
    __builtin_nontemporal_store(o, dst);
}

extern "C" void kernel_launch(void* const* d_in, const int* in_sizes, int n_in,
                              void* d_out, int out_size, void* d_ws, size_t ws_size,
                              hipStream_t stream) {
    const float* x   = (const float*)d_in[0];
    const float* wts = (const float*)d_in[1];
    float* out = (float*)d_out;

    int total_threads = BB * CC * HH * W4;     // 16,777,216
    int block = 256;
    int grid = total_threads / block;          // 65,536
    morph_dilate_kernel<<<grid, block, 0, stream>>>(x, wts, out);
}

// Round 4
// 421.415 us; speedup vs baseline: 1.1418x; 1.1418x over previous
//
#include <hip/hip_runtime.h>

// Morphological dilation (max-plus 3x3 conv), zero-padded.
// x: (B=4, C=64, H=512, W=512) fp32, weights: (C=64, 3, 3) fp32.
// out[b,c,h,w] = max_{i,j in 0..2} ( xp[b,c,h-1+i,w-1+j] + wt[c,i,j] ),
// zero-padded (nn.Unfold semantics) — padded zeros DO participate.
//
// R4: each thread computes a 4(rows)x4(cols) output tile. 6 input rows
// loaded once per thread (vertical reuse 3x vs 1-row version). Plain
// (cached) stores — NT store was suspect for low write BW in R3.

#define BB 4
#define CC 64
#define HH 512
#define WW 512
#define W4 (WW / 4)   // 128 col-groups
#define RB 4          // output rows per thread
#define HB (HH / RB)  // 128 row-blocks

typedef float vfloat4 __attribute__((ext_vector_type(4)));

__global__ __launch_bounds__(256) void morph_dilate_kernel(
    const float* __restrict__ x,
    const float* __restrict__ wts,
    float* __restrict__ out) {
    int tid = blockIdx.x * blockDim.x + threadIdx.x;
    // total threads = B*C * HB * W4 = 256*128*128 = 4,194,304
    int wi    = tid & (W4 - 1);          // col-group 0..127
    int w4    = wi * 4;
    int hb    = (tid >> 7) & (HB - 1);   // row-block 0..127
    int h0    = hb * RB;
    int plane = tid >> 14;               // b*C + c, 0..255
    int c     = plane & (CC - 1);

    const float* xplane = x + (size_t)plane * (HH * WW);
    const float* wt = wts + c * 9;

    float w00 = wt[0], w01 = wt[1], w02 = wt[2];
    float w10 = wt[3], w11 = wt[4], w12 = wt[5];
    float w20 = wt[6], w21 = wt[7], w22 = wt[8];

    // load 6 input rows (h0-1 .. h0+4): 6 floats each (w4-1 .. w4+4)
    float v[6][6];
#pragma unroll
    for (int i = 0; i < 6; ++i) {
        int r = h0 - 1 + i;
        if (r >= 0 && r < HH) {
            const float* xrow = xplane + r * WW;
            v[i][0] = (w4 > 0) ? xrow[w4 - 1] : 0.0f;
            vfloat4 mid = *reinterpret_cast<const vfloat4*>(xrow + w4);
            v[i][1] = mid.x; v[i][2] = mid.y; v[i][3] = mid.z; v[i][4] = mid.w;
            v[i][5] = (w4 + 4 < WW) ? xrow[w4 + 4] : 0.0f;
        } else {
#pragma unroll
            for (int j = 0; j < 6; ++j) v[i][j] = 0.0f;
        }
    }

    float* oplane = out + (size_t)plane * (HH * WW);
#pragma unroll
    for (int rt = 0; rt < RB; ++rt) {
        vfloat4 o;
#pragma unroll
        for (int t = 0; t < 4; ++t) {
            float m;
            m =          v[rt + 0][t + 0] + w00;
            m = fmaxf(m, v[rt + 0][t + 1] + w01);
            m = fmaxf(m, v[rt + 0][t + 2] + w02);
            m = fmaxf(m, v[rt + 1][t + 0] + w10);
            m = fmaxf(m, v[rt + 1][t + 1] + w11);
            m = fmaxf(m, v[rt + 1][t + 2] + w12);
            m = fmaxf(m, v[rt + 2][t + 0] + w20);
            m = fmaxf(m, v[rt + 2][t + 1] + w21);
            m = fmaxf(m, v[rt + 2][t + 2] + w22);
            o[t] = m;
        }
        *reinterpret_cast<vfloat4*>(oplane + (size_t)(h0 + rt) * WW + w4) = o;
    }
}

extern "C" void kernel_launch(void* const* d_in, const int* in_sizes, int n_in,
                              void* d_out, int out_size, void* d_ws, size_t ws_size,
                              hipStream_t stream) {
    const float* x   = (const float*)d_in[0];
    const float* wts = (const float*)d_in[1];
    float* out = (float*)d_out;

    int total_threads = BB * CC * HB * W4;   // 4,194,304
    int block = 256;
    int grid = total_threads / block;        // 16,384
    morph_dilate_kernel<<<grid, block, 0, stream>>>(x, wts, out);
}